// Round 14
// baseline (48.758 us; speedup 1.0000x reference)
//
#include <hip/hip_runtime.h>
#include <cfloat>

// ---------------------------------------------------------------------------
// VQ-VAE vector quantizer forward (MI355X / gfx950)
//   x        [32][64][64][64] f32   (B, D, H, W)
//   codebook [1024][64] f32
// out: x_q transposed back to [B,D,H,W] (8388608 f32)  +  loss scalar (1 f32)
//
// argmin_k ||x - c_k||^2  ==  argmax_k (x . c_k - ||c_k||^2/2)
// Sum_p SSE_p = Sum x^2 - 2 * Sum_p (best_score_p - 1),
//   score = dot + 1 - ||c||^2/2 (C-init), packed-u32 argmax (R5/R9-proven).
//
// R14 = R13 with wave decomposition (code-quarter) -> (code-half x pos-half)
// to free registers (afrag 32->16, best 16->8) and spend them on DEPTH-2
// ping-pong B/mh prefetch (~250-300cyc L2 latency now covered by 2 iters of
// compute) while staying UNDER the 64-VGPR cliff (waves/SIMD halve at 65).
// Cost: each B tile read by 2 waves (B L2 traffic x2) -- acceptable, cb_frag
// is XCD-L2-hot. Staging / argmax / loss / epilogue / vq_pre unchanged.
// Canaries: VGPR<=64, FETCH~18.6MB, WRITE~32.8MB.
// ---------------------------------------------------------------------------

#define DD   64
#define HHWW 4096          // H*W
#define KC   1024
#define NBLK  2048         // one block per (b,h) row
#define NPOSD 8388608.0f   // N * D

typedef __bf16  bf16x8 __attribute__((ext_vector_type(8)));
typedef float   f32x4  __attribute__((ext_vector_type(4)));

__device__ __forceinline__ unsigned short bf16_bits(float f) {
  unsigned u = __float_as_uint(f);
  return (unsigned short)((u + 0x7FFFu + ((u >> 16) & 1u)) >> 16);  // RNE
}

__device__ __forceinline__ unsigned int umax2(unsigned int a, unsigned int b) {
  return a > b ? a : b;
}

// --- precompute: fragment-ordered bf16 codebook + replicated (1-||c||^2/2) --
// thread = (code k, dim-quad q); coalesced float4 read, 16-lane shfl reduce.
__global__ __launch_bounds__(256) void vq_pre(
    const float* __restrict__ cb,          // [1024][64]
    unsigned short* __restrict__ cb_frag,  // [tile=64][kk=2][lane=64][e=8]
    float* __restrict__ hneg4)             // [1024][4] : 1-||c||^2/2, x4
{
  const int gt = blockIdx.x * 256 + threadIdx.x;  // 0..16383
  const int k  = gt >> 4;                          // code 0..1023
  const int q  = gt & 15;                          // dim quad 0..15
  const float4 v = *(const float4*)(cb + (size_t)k * DD + q * 4);

  float s = v.x * v.x + v.y * v.y + v.z * v.z + v.w * v.w;
#pragma unroll
  for (int m = 1; m < 16; m <<= 1) s += __shfl_xor(s, m, 64);  // 16-group sum
  if (q == 0) {
    const float mval = 1.0f - 0.5f * s;
    float4 m4; m4.x = mval; m4.y = mval; m4.z = mval; m4.w = mval;
    *(float4*)(hneg4 + (size_t)k * 4) = m4;
  }

  const int d0 = q * 4;
  const int kk = d0 >> 5, g = (d0 >> 3) & 3, e0 = d0 & 7;
  const int t = k >> 4, l15 = k & 15;
  unsigned short u0 = bf16_bits(v.x), u1 = bf16_bits(v.y);
  unsigned short u2 = bf16_bits(v.z), u3 = bf16_bits(v.w);
  uint2 wv2;
  wv2.x = (unsigned int)u0 | ((unsigned int)u1 << 16);
  wv2.y = (unsigned int)u2 | ((unsigned int)u3 << 16);
  *(uint2*)(&cb_frag[(((t * 2 + kk) * 64) + (g * 16 + l15)) * 8 + e0]) = wv2;
}

// --- main: fused distance-GEMM + argmin + loss partial + output write ------
__global__ __launch_bounds__(256) void vq_main(
    const float* __restrict__ x,
    const unsigned short* __restrict__ cb_frag,
    const float* __restrict__ hneg4,
    const float* __restrict__ cb,
    float* __restrict__ out,
    float* __restrict__ partials)
{
  __shared__ unsigned short xfrag[4096];   //  8 KB: row A-fragments (bf16)
  __shared__ unsigned int   cand[2][64];   // 512 B: per-code-half winners
  __shared__ int            idx_lds[64];
  __shared__ float          xred[4];

  const int tid  = threadIdx.x;
  const int wv   = tid >> 6;
  const int lane = tid & 63;
  const int l15  = lane & 15;
  const int cw   = wv & 1;     // code half: 512 codes (32 tiles)
  const int pw   = wv >> 1;    // pos half: pos-tiles {pw*2, pw*2+1}

  // XCD-aware swizzle (bijective; keeps cb tables hot per-XCD L2)
  const int row = ((blockIdx.x & 7) << 8) + (blockIdx.x >> 3);
  const int b   = row >> 6;
  const int h   = row & 63;
  const float* xb = x + (size_t)b * DD * HHWW + h * 64;  // xb[d*4096 + w]

  // ---- cooperative coalesced x-stage -> bf16 fragment layout in LDS ----
  // XOR-swizzle (l15 ^ pt) on write AND read (bank-conflict fix, R12-proven).
  float xacc = 0.f;
#pragma unroll
  for (int r4 = 0; r4 < 4; ++r4) {
    const int m  = tid + r4 * 256;
    const int d  = m >> 4;
    const int w4 = m & 15;
    const float4 v4 = *(const float4*)(xb + (size_t)d * HHWW + w4 * 4);
    const int kk = d >> 5, gg = (d >> 3) & 3, e = d & 7;
    const int pt = w4 >> 2;
    const int base = pt * 1024 + kk * 512 + gg * 128 + e;  // + (l15^pt)*8
    const int lb = (w4 & 3) * 4;                           // l15 = lb + i
    xacc += v4.x * v4.x + v4.y * v4.y + v4.z * v4.z + v4.w * v4.w;
    xfrag[base + ((lb + 0) ^ pt) * 8] = bf16_bits(v4.x);
    xfrag[base + ((lb + 1) ^ pt) * 8] = bf16_bits(v4.y);
    xfrag[base + ((lb + 2) ^ pt) * 8] = bf16_bits(v4.z);
    xfrag[base + ((lb + 3) ^ pt) * 8] = bf16_bits(v4.w);
  }

  __syncthreads();                       // xfrag ready

  // ---- A fragments: this wave's 2 pos-tiles (b128, XOR-matched) ----
  const int g = lane >> 4;
  bf16x8 afrag[2][2];
#pragma unroll
  for (int j = 0; j < 2; ++j) {
    const int pt = pw * 2 + j;
    const int ls = g * 16 + (l15 ^ pt);
    afrag[j][0] = *(const bf16x8*)(&xfrag[pt * 1024 + ls * 8]);
    afrag[j][1] = *(const bf16x8*)(&xfrag[pt * 1024 + 512 + ls * 8]);
  }

  // ---- this wave's 32 code tiles (codes cw*512 .. +511), DEPTH-2 pf ----
  unsigned int best[2][4];
#pragma unroll
  for (int j = 0; j < 2; ++j)
#pragma unroll
    for (int rr = 0; rr < 4; ++rr) best[j][rr] = 0u;

  const unsigned int MASK = 0xFFFFFC00u;
  const int codec0 = 1023 - cw * 512 - l15;
  const char*  bb  = (const char*)cb_frag + (size_t)cw * 32 * 2048 + (size_t)lane * 16;
  const f32x4* mhp = (const f32x4*)hneg4 + cw * 512 + l15;   // + t*16 per tile

  // depth-2 ping-pong slots (slot = t&1, static under unroll 4)
  bf16x8 pb0[2], pb1[2];
  f32x4  pmh[2];
#pragma unroll
  for (int s = 0; s < 2; ++s) {
    pb0[s] = *(const bf16x8*)(bb + s * 2048);
    pb1[s] = *(const bf16x8*)(bb + s * 2048 + 1024);
    pmh[s] = mhp[s * 16];
  }

#pragma unroll 4
  for (int t = 0; t < 32; ++t) {
    const int s = t & 1;                 // static per unrolled instance
    const bf16x8 b0 = pb0[s], b1 = pb1[s];
    const f32x4  mh = pmh[s];
    const int tn = (t + 2) & 31;         // wrap-reload at tail (values unused)
    pb0[s] = *(const bf16x8*)(bb + tn * 2048);
    pb1[s] = *(const bf16x8*)(bb + tn * 2048 + 1024);
    pmh[s] = mhp[tn * 16];

    const unsigned int codec = (unsigned int)(codec0 - t * 16);

#pragma unroll
    for (int j = 0; j < 2; ++j) {
      f32x4 acc = __builtin_amdgcn_mfma_f32_16x16x32_bf16(afrag[j][0], b0, mh, 0, 0, 0);
      acc = __builtin_amdgcn_mfma_f32_16x16x32_bf16(afrag[j][1], b1, acc, 0, 0, 0);
#pragma unroll
      for (int rr = 0; rr < 4; ++rr) {  // C/D: col=l15(code), row=g*4+rr(pos)
        const unsigned int p = (__float_as_uint(acc[rr]) & MASK) | codec;
        best[j][rr] = umax2(best[j][rr], p);   // v_and_or + v_max
      }
    }
  }

  // ---- cross-lane max over the 16 code columns (l15) ----
#pragma unroll
  for (int j = 0; j < 2; ++j)
#pragma unroll
    for (int rr = 0; rr < 4; ++rr) {
      unsigned int v = best[j][rr];
#pragma unroll
      for (int m = 1; m < 16; m <<= 1) {
        unsigned int vo = __shfl_xor(v, m, 64);
        v = umax2(v, vo);
      }
      // position = (pw*2+j)*16 + g*4 + rr ; two pw-waves cover disjoint halves
      if (l15 == 0) cand[cw][pw * 32 + j * 16 + g * 4 + rr] = v;
    }

  // per-wave Sum x^2 reduce (staging was split over all 256 threads)
#pragma unroll
  for (int m = 1; m < 64; m <<= 1) xacc += __shfl_xor(xacc, m, 64);
  if (lane == 0) xred[wv] = xacc;

  __syncthreads();

  // ---- wave 0: merge the 2 code-half candidates; loss partial ----
  if (tid < 64) {
    const unsigned int v = umax2(cand[0][tid], cand[1][tid]);
    idx_lds[tid] = 1023 - (int)(v & 1023u);
    float vt1 = __uint_as_float(v & MASK) - 1.0f;   // dot - csq/2 (trunc)
#pragma unroll
    for (int m = 1; m < 64; m <<= 1) vt1 += __shfl_xor(vt1, m, 64);
    if (tid == 0)
      partials[blockIdx.x] =
          (xred[0] + xred[1] + xred[2] + xred[3]) - 2.0f * vt1;
  }

  __syncthreads();

  // ---- write quantized output; float4 gather from row-major cb ----
  const int myidx = idx_lds[lane];       // position w = lane
  const float4* crow = (const float4*)(cb + (size_t)myidx * DD) + wv * 4;
  const float4 c0 = crow[0], c1 = crow[1], c2 = crow[2], c3 = crow[3];
  float* ob = out + (size_t)b * DD * HHWW + h * 64 + lane;
  ob[(size_t)(wv * 16 +  0) * HHWW] = c0.x;
  ob[(size_t)(wv * 16 +  1) * HHWW] = c0.y;
  ob[(size_t)(wv * 16 +  2) * HHWW] = c0.z;
  ob[(size_t)(wv * 16 +  3) * HHWW] = c0.w;
  ob[(size_t)(wv * 16 +  4) * HHWW] = c1.x;
  ob[(size_t)(wv * 16 +  5) * HHWW] = c1.y;
  ob[(size_t)(wv * 16 +  6) * HHWW] = c1.z;
  ob[(size_t)(wv * 16 +  7) * HHWW] = c1.w;
  ob[(size_t)(wv * 16 +  8) * HHWW] = c2.x;
  ob[(size_t)(wv * 16 +  9) * HHWW] = c2.y;
  ob[(size_t)(wv * 16 + 10) * HHWW] = c2.z;
  ob[(size_t)(wv * 16 + 11) * HHWW] = c2.w;
  ob[(size_t)(wv * 16 + 12) * HHWW] = c3.x;
  ob[(size_t)(wv * 16 + 13) * HHWW] = c3.y;
  ob[(size_t)(wv * 16 + 14) * HHWW] = c3.z;
  ob[(size_t)(wv * 16 + 15) * HHWW] = c3.w;
}

// --- final loss reduce ------------------------------------------------------
__global__ __launch_bounds__(256) void vq_loss(
    const float* __restrict__ partials, float* __restrict__ loss_out)
{
  __shared__ float sred[4];
  int tid = threadIdx.x;
  float s = 0.f;
  for (int i = tid; i < NBLK; i += 256) s += partials[i];
#pragma unroll
  for (int m = 1; m < 64; m <<= 1) s += __shfl_xor(s, m, 64);
  if ((tid & 63) == 0) sred[tid >> 6] = s;
  __syncthreads();
  if (tid == 0)
    loss_out[0] = (sred[0] + sred[1] + sred[2] + sred[3]) * (1.25f / NPOSD);
}

extern "C" void kernel_launch(void* const* d_in, const int* in_sizes, int n_in,
                              void* d_out, int out_size, void* d_ws, size_t ws_size,
                              hipStream_t stream) {
  const float* x  = (const float*)d_in[0];
  const float* cb = (const float*)d_in[1];
  float* out      = (float*)d_out;
  float* loss_out = out + 8388608;

  char* ws = (char*)d_ws;
  unsigned short* cb_frag = (unsigned short*)(ws);      // 131072 B
  float* hneg4    = (float*)(ws + 131072);              //  16384 B
  float* partials = (float*)(ws + 147456);              //   8192 B

  vq_pre <<<64,   256, 0, stream>>>(cb, cb_frag, hneg4);
  vq_main<<<NBLK, 256, 0, stream>>>(x, cb_frag, hneg4, cb, out, partials);
  vq_loss<<<1,    256, 0, stream>>>(partials, loss_out);
}

// Round 15
// 46.711 us; speedup vs baseline: 1.0438x; 1.0438x over previous
//
#include <hip/hip_runtime.h>
#include <cfloat>

// ---------------------------------------------------------------------------
// VQ-VAE vector quantizer forward (MI355X / gfx950)
//   x        [32][64][64][64] f32   (B, D, H, W)
//   codebook [1024][64] f32
// out: x_q transposed back to [B,D,H,W] (8388608 f32)  +  loss scalar (1 f32)
//
// argmin_k ||x - c_k||^2  ==  argmax_k (x . c_k - ||c_k||^2/2)
// Sum_p SSE_p = Sum x^2 - 2 * Sum_p (best_score_p - 1),
//   score = dot + 1 - ||c||^2/2 (C-init), packed-u32 argmax (R5/R9-proven).
//
// R15: LDS-staged B (kills the per-iteration L2 request storm that kept
// VALUBusy at 35%). Block = 2 rows, 4 waves; wave = (row, 16-pos half),
// scans ALL 1024 codes -> no cross-wave candidate merge. cb_frag staged in
// double-buffered 8-tile (16 KB) phases via global_load_lds, ONE barrier
// per phase (R3's structure but 4x coarser phases + 2x arithmetic
// intensity). Pair-merge via v_max3_u32 (12 VALU/tile vs 16). mh4 from
// global (L2-hot, depth-1; R12-proven). LDS ~50 KB -> 3 blocks/CU; VGPR
// has headroom to 128 without residency loss (LDS is the cap) -> no
// launch_bounds hint, no spill risk.
// Canaries: WRITE~33MB (spill), conflicts<500K, LDS~50KB.
// ---------------------------------------------------------------------------

#define DD    64
#define HHWW  4096         // H*W
#define KC    1024
#define NBLKM 1024         // one block per 2 rows
#define NPOSD 8388608.0f   // N * D

typedef __bf16  bf16x8 __attribute__((ext_vector_type(8)));
typedef float   f32x4  __attribute__((ext_vector_type(4)));

__device__ __forceinline__ unsigned short bf16_bits(float f) {
  unsigned u = __float_as_uint(f);
  return (unsigned short)((u + 0x7FFFu + ((u >> 16) & 1u)) >> 16);  // RNE
}

__device__ __forceinline__ unsigned int umax2(unsigned int a, unsigned int b) {
  return a > b ? a : b;
}

// global->LDS direct copy, 16B per lane. ldst wave-uniform; HW adds lane*16.
__device__ __forceinline__ void gload_lds16(const void* gsrc, void* ldst) {
  __builtin_amdgcn_global_load_lds(
      (const __attribute__((address_space(1))) unsigned int*)gsrc,
      (__attribute__((address_space(3))) unsigned int*)ldst, 16, 0, 0);
}

// --- precompute: fragment-ordered bf16 codebook + replicated (1-||c||^2/2) --
// thread = (code k, dim-quad q); coalesced float4 read, 16-lane shfl reduce.
__global__ __launch_bounds__(256) void vq_pre(
    const float* __restrict__ cb,          // [1024][64]
    unsigned short* __restrict__ cb_frag,  // [tile=64][kk=2][lane=64][e=8]
    float* __restrict__ hneg4)             // [1024][4] : 1-||c||^2/2, x4
{
  const int gt = blockIdx.x * 256 + threadIdx.x;  // 0..16383
  const int k  = gt >> 4;                          // code 0..1023
  const int q  = gt & 15;                          // dim quad 0..15
  const float4 v = *(const float4*)(cb + (size_t)k * DD + q * 4);

  float s = v.x * v.x + v.y * v.y + v.z * v.z + v.w * v.w;
#pragma unroll
  for (int m = 1; m < 16; m <<= 1) s += __shfl_xor(s, m, 64);  // 16-group sum
  if (q == 0) {
    const float mval = 1.0f - 0.5f * s;
    float4 m4; m4.x = mval; m4.y = mval; m4.z = mval; m4.w = mval;
    *(float4*)(hneg4 + (size_t)k * 4) = m4;
  }

  const int d0 = q * 4;
  const int kk = d0 >> 5, g = (d0 >> 3) & 3, e0 = d0 & 7;
  const int t = k >> 4, l15 = k & 15;
  unsigned short u0 = bf16_bits(v.x), u1 = bf16_bits(v.y);
  unsigned short u2 = bf16_bits(v.z), u3 = bf16_bits(v.w);
  uint2 wv2;
  wv2.x = (unsigned int)u0 | ((unsigned int)u1 << 16);
  wv2.y = (unsigned int)u2 | ((unsigned int)u3 << 16);
  *(uint2*)(&cb_frag[(((t * 2 + kk) * 64) + (g * 16 + l15)) * 8 + e0]) = wv2;
}

// --- main: fused distance-GEMM + argmin + loss partial + output write ------
__global__ __launch_bounds__(256) void vq_main(
    const float* __restrict__ x,
    const unsigned short* __restrict__ cb_frag,
    const float* __restrict__ hneg4,
    const float* __restrict__ cb,
    float* __restrict__ out,
    float* __restrict__ partials)
{
  __shared__ unsigned short cbbuf[2][8192];  // 2 x 16 KB: 8-tile phases
  __shared__ unsigned short xfrag[2][4096];  // 16 KB: A-frags, 2 rows
  __shared__ int            idx_lds[2][64];
  __shared__ float          xred[4];
  __shared__ float          vtred[4];

  const int tid  = threadIdx.x;
  const int wv   = tid >> 6;
  const int lane = tid & 63;
  const int l15  = lane & 15;
  const int g    = lane >> 4;
  const int rw   = wv >> 1;    // row within block (0..1)
  const int phf  = wv & 1;     // pos half: pos-tiles {phf*2, phf*2+1}

  // XCD-aware swizzle over 1024 blocks (bijective)
  const int row0 = (((blockIdx.x & 7) << 7) + (blockIdx.x >> 3)) * 2;
  const int b    = row0 >> 6;
  const int h0   = row0 & 63;
  const float* xb = x + (size_t)b * DD * HHWW + h0 * 64;  // xb[d*4096 + w]

  // ---- stage phase 0 of cb (16 KB) via async global_load_lds ----
#pragma unroll
  for (int i = 0; i < 4; ++i)
    gload_lds16((const char*)cb_frag + i * 4096 + (size_t)tid * 16,
                (char*)cbbuf[0] + i * 4096 + wv * 1024);

  // ---- cooperative coalesced x-stage (2 rows) -> bf16 frag layout ----
  // XOR-swizzle (l15 ^ pt) on write AND read (bank-conflict fix, R12-proven).
  float xacc = 0.f;
#pragma unroll
  for (int r = 0; r < 2; ++r) {
#pragma unroll
    for (int r4 = 0; r4 < 4; ++r4) {
      const int m  = tid + r4 * 256;
      const int d  = m >> 4;
      const int w4 = m & 15;
      const float4 v4 = *(const float4*)(xb + (size_t)d * HHWW + r * 64 + w4 * 4);
      const int kk = d >> 5, gg = (d >> 3) & 3, e = d & 7;
      const int pt = w4 >> 2;
      const int base = pt * 1024 + kk * 512 + gg * 128 + e;  // + (l15^pt)*8
      const int lb = (w4 & 3) * 4;
      xacc += v4.x * v4.x + v4.y * v4.y + v4.z * v4.z + v4.w * v4.w;
      xfrag[r][base + ((lb + 0) ^ pt) * 8] = bf16_bits(v4.x);
      xfrag[r][base + ((lb + 1) ^ pt) * 8] = bf16_bits(v4.y);
      xfrag[r][base + ((lb + 2) ^ pt) * 8] = bf16_bits(v4.z);
      xfrag[r][base + ((lb + 3) ^ pt) * 8] = bf16_bits(v4.w);
    }
  }

  // mh4 depth-1 prefetch (tiles 0,1) while the barrier drains
  const f32x4* mhp = (const f32x4*)hneg4 + l15;   // + tile*16
  f32x4 nmhA = mhp[0];
  f32x4 nmhB = mhp[16];

  __syncthreads();                       // cbbuf[0], xfrag ready

  // ---- A fragments: this wave's 2 pos-tiles of row rw ----
  bf16x8 afrag[2][2];
#pragma unroll
  for (int j = 0; j < 2; ++j) {
    const int pt = phf * 2 + j;
    const int ls = g * 16 + (l15 ^ pt);
    afrag[j][0] = *(const bf16x8*)(&xfrag[rw][pt * 1024 + ls * 8]);
    afrag[j][1] = *(const bf16x8*)(&xfrag[rw][pt * 1024 + 512 + ls * 8]);
  }

  // ---- scan all 64 tiles: 8 phases x (4 tile-pairs), packed-u32 argmax ----
  unsigned int best[2][4];
#pragma unroll
  for (int j = 0; j < 2; ++j)
#pragma unroll
    for (int rr = 0; rr < 4; ++rr) best[j][rr] = 0u;

  const unsigned int MASK = 0xFFFFFC00u;
  const int codec0 = 1023 - l15;

  for (int ph = 0; ph < 8; ++ph) {
    // prefetch next phase into the other buffer (async; barrier drains it)
    if (ph < 7) {
#pragma unroll
      for (int i = 0; i < 4; ++i)
        gload_lds16((const char*)cb_frag + (ph + 1) * 16384 + i * 4096 + (size_t)tid * 16,
                    (char*)cbbuf[(ph + 1) & 1] + i * 4096 + wv * 1024);
    }

    const unsigned short* bufc = cbbuf[ph & 1];
#pragma unroll
    for (int pr = 0; pr < 4; ++pr) {
      const int tA = ph * 8 + pr * 2;    // global tile of pair (A, B=A+1)
      const bf16x8 bA0 = *(const bf16x8*)(bufc + pr * 2048 + lane * 8);
      const bf16x8 bA1 = *(const bf16x8*)(bufc + pr * 2048 + 512 + lane * 8);
      const bf16x8 bB0 = *(const bf16x8*)(bufc + pr * 2048 + 1024 + lane * 8);
      const bf16x8 bB1 = *(const bf16x8*)(bufc + pr * 2048 + 1536 + lane * 8);
      const f32x4 mhA = nmhA, mhB = nmhB;
      const int tn = (tA + 2) & 63;      // prefetch mh for next pair
      nmhA = mhp[tn * 16];
      nmhB = mhp[(tn + 1) * 16];

      const unsigned int codecA = (unsigned int)(codec0 - tA * 16);
      const unsigned int codecB = (unsigned int)(codec0 - (tA + 1) * 16);

#pragma unroll
      for (int j = 0; j < 2; ++j) {
        f32x4 aA = __builtin_amdgcn_mfma_f32_16x16x32_bf16(afrag[j][0], bA0, mhA, 0, 0, 0);
        aA = __builtin_amdgcn_mfma_f32_16x16x32_bf16(afrag[j][1], bA1, aA, 0, 0, 0);
        f32x4 aB = __builtin_amdgcn_mfma_f32_16x16x32_bf16(afrag[j][0], bB0, mhB, 0, 0, 0);
        aB = __builtin_amdgcn_mfma_f32_16x16x32_bf16(afrag[j][1], bB1, aB, 0, 0, 0);
#pragma unroll
        for (int rr = 0; rr < 4; ++rr) { // C/D: col=l15(code), row=g*4+rr(pos)
          const unsigned int pA_ = (__float_as_uint(aA[rr]) & MASK) | codecA;
          const unsigned int pB_ = (__float_as_uint(aB[rr]) & MASK) | codecB;
          best[j][rr] = umax2(umax2(best[j][rr], pA_), pB_);  // v_max3_u32
        }
      }
    }
    __syncthreads();   // staging(ph+1) done; everyone done reading cbbuf[ph&1]
  }

  // ---- cross-lane argmax over the 16 code columns (l15); vt accumulate ----
  float vtacc = 0.f;
#pragma unroll
  for (int j = 0; j < 2; ++j)
#pragma unroll
    for (int rr = 0; rr < 4; ++rr) {
      unsigned int v = best[j][rr];
#pragma unroll
      for (int m = 1; m < 16; m <<= 1) {
        unsigned int vo = __shfl_xor(v, m, 64);
        v = umax2(v, vo);
      }
      if (l15 == 0) {
        idx_lds[rw][(phf * 2 + j) * 16 + g * 4 + rr] = 1023 - (int)(v & 1023u);
        vtacc += __uint_as_float(v & MASK) - 1.0f;   // dot - csq/2 (trunc)
      }
    }

  // per-wave reduces: Sum x^2 (all lanes) and Sum(vt-1) (l15==0 lanes)
#pragma unroll
  for (int m = 1; m < 64; m <<= 1) {
    xacc  += __shfl_xor(xacc, m, 64);
    vtacc += __shfl_xor(vtacc, m, 64);
  }
  if (lane == 0) { xred[wv] = xacc; vtred[wv] = vtacc; }

  __syncthreads();                       // idx_lds + reduces ready

  if (tid == 0)
    partials[blockIdx.x] =
        (xred[0] + xred[1] + xred[2] + xred[3]) -
        2.0f * (vtred[0] + vtred[1] + vtred[2] + vtred[3]);

  // ---- write quantized output; float4 gather from row-major cb ----
#pragma unroll
  for (int r = 0; r < 2; ++r) {
    const int myidx = idx_lds[r][lane];  // position w = lane
    const float4* crow = (const float4*)(cb + (size_t)myidx * DD) + wv * 4;
    const float4 c0 = crow[0], c1 = crow[1], c2 = crow[2], c3 = crow[3];
    float* ob = out + (size_t)b * DD * HHWW + (h0 + r) * 64 + lane;
    ob[(size_t)(wv * 16 +  0) * HHWW] = c0.x;
    ob[(size_t)(wv * 16 +  1) * HHWW] = c0.y;
    ob[(size_t)(wv * 16 +  2) * HHWW] = c0.z;
    ob[(size_t)(wv * 16 +  3) * HHWW] = c0.w;
    ob[(size_t)(wv * 16 +  4) * HHWW] = c1.x;
    ob[(size_t)(wv * 16 +  5) * HHWW] = c1.y;
    ob[(size_t)(wv * 16 +  6) * HHWW] = c1.z;
    ob[(size_t)(wv * 16 +  7) * HHWW] = c1.w;
    ob[(size_t)(wv * 16 +  8) * HHWW] = c2.x;
    ob[(size_t)(wv * 16 +  9) * HHWW] = c2.y;
    ob[(size_t)(wv * 16 + 10) * HHWW] = c2.z;
    ob[(size_t)(wv * 16 + 11) * HHWW] = c2.w;
    ob[(size_t)(wv * 16 + 12) * HHWW] = c3.x;
    ob[(size_t)(wv * 16 + 13) * HHWW] = c3.y;
    ob[(size_t)(wv * 16 + 14) * HHWW] = c3.z;
    ob[(size_t)(wv * 16 + 15) * HHWW] = c3.w;
  }
}

// --- final loss reduce ------------------------------------------------------
__global__ __launch_bounds__(256) void vq_loss(
    const float* __restrict__ partials, float* __restrict__ loss_out)
{
  __shared__ float sred[4];
  int tid = threadIdx.x;
  float s = 0.f;
  for (int i = tid; i < NBLKM; i += 256) s += partials[i];
#pragma unroll
  for (int m = 1; m < 64; m <<= 1) s += __shfl_xor(s, m, 64);
  if ((tid & 63) == 0) sred[tid >> 6] = s;
  __syncthreads();
  if (tid == 0)
    loss_out[0] = (sred[0] + sred[1] + sred[2] + sred[3]) * (1.25f / NPOSD);
}

extern "C" void kernel_launch(void* const* d_in, const int* in_sizes, int n_in,
                              void* d_out, int out_size, void* d_ws, size_t ws_size,
                              hipStream_t stream) {
  const float* x  = (const float*)d_in[0];
  const float* cb = (const float*)d_in[1];
  float* out      = (float*)d_out;
  float* loss_out = out + 8388608;

  char* ws = (char*)d_ws;
  unsigned short* cb_frag = (unsigned short*)(ws);      // 131072 B
  float* hneg4    = (float*)(ws + 131072);              //  16384 B
  float* partials = (float*)(ws + 147456);              //   8192 B

  vq_pre <<<64,    256, 0, stream>>>(cb, cb_frag, hneg4);
  vq_main<<<NBLKM, 256, 0, stream>>>(x, cb_frag, hneg4, cb, out, partials);
  vq_loss<<<1,     256, 0, stream>>>(partials, loss_out);
}